// Round 2
// baseline (507.141 us; speedup 1.0000x reference)
//
#include <hip/hip_runtime.h>
#include <hip/hip_bf16.h>
#include <math.h>

typedef __bf16 bf16_t;
typedef __bf16 bf16x8 __attribute__((ext_vector_type(8)));
typedef float  f32x4  __attribute__((ext_vector_type(4)));

#define MINST 50000

typedef const __attribute__((address_space(1))) void* gas1_t;
typedef __attribute__((address_space(3))) void* las3_t;
__device__ __forceinline__ void gload16(const void* g, const void* l){
  __builtin_amdgcn_global_load_lds((gas1_t)g, (las3_t)l, 16, 0, 0);
}

__device__ __forceinline__ float fast_sigmoid(float x){
  return __fdividef(1.f, 1.f + __expf(-x));
}
__device__ __forceinline__ float fast_tanh(float x){
  float e = __expf(2.f*x);
  return 1.f - __fdividef(2.f, e + 1.f);
}

// ---------- prep: W[1024][512] -> WT[512][1024] bf16 ----------
__global__ void prep_wt(const float* __restrict__ W, bf16_t* __restrict__ WT){
  int idx = blockIdx.x*256 + threadIdx.x;
  if (idx >= 512*1024) return;
  int n = idx >> 10, k = idx & 1023;
  WT[idx] = (bf16_t)W[k*512 + n];
}

// ---------- prep: Ua/Ub[4][512][256] -> UabT[2048][512] bf16, cols interleaved ----------
__global__ void prep_uab(const float* __restrict__ Ua, const float* __restrict__ Ub,
                         bf16_t* __restrict__ UabT){
  int idx = blockIdx.x*256 + threadIdx.x;
  if (idx >= 2048*512) return;
  int c = idx >> 9, k = idx & 511;
  int s = c & 1, t = c >> 1;
  int n = t >> 8, l = t & 255;
  const float* src = s ? Ub : Ua;
  UabT[idx] = (bf16_t)src[(n*512 + k)*256 + l];
}

__global__ void zero_ws_k(float* __restrict__ Alogit, float* __restrict__ Mbuf){
  int i = blockIdx.x*256 + threadIdx.x;
  if (i < MINST) Alogit[i] = 0.f;
  if (i < 513)   Mbuf[i]  = 0.f;
}

// ---------- MFMA GEMM, 128x128 tile, BK=32, 4 waves (2x2), linear LDS + global_load_lds ----------
// EPI=0: A f32 (reg-staged cvt), relu+bias -> bf16 Xout.  EPI=1: A bf16 via global_load_lds, attn epilogue.
template<int EPI, int K, int NBY>
__global__ __launch_bounds__(256, 2)
void gemm_k(const void* __restrict__ Ap, const bf16_t* __restrict__ Bp, int M,
            const float* __restrict__ bias, bf16_t* __restrict__ Xout,
            const float* __restrict__ Uc, float* __restrict__ Alogit)
{
  __shared__ bf16_t As[(EPI==0?1:2)][128*32] __attribute__((aligned(16)));
  __shared__ bf16_t Bs[2][128*32] __attribute__((aligned(16)));

  const int tid  = threadIdx.x;
  const int lane = tid & 63;
  const int w    = tid >> 6;
  const int wr   = w >> 1;
  const int wc   = w & 1;

  // bijective XCD-chunk swizzle (m204): all NBY col-blocks of a row-panel on one XCD, consecutively
  const int nwg = gridDim.x;
  const int q = nwg >> 3, r = nwg & 7;
  const int x = blockIdx.x & 7, pos = blockIdx.x >> 3;
  const int logical = (x < r ? x*(q+1) : r*(q+1) + (x-r)*q) + pos;
  const int m0 = (logical / NBY) * 128;
  const int n0 = (logical % NBY) * 128;

  const f32x4 fzero = {0.f, 0.f, 0.f, 0.f};
  f32x4 acc[4][4];
#pragma unroll
  for (int m = 0; m < 4; ++m)
#pragma unroll
    for (int n = 0; n < 4; ++n) acc[m][n] = fzero;

  // staging source pointers (per-lane): 16 rows x 64B per instruction
  const int srow = lane >> 2;          // 0..15
  const int schk = (lane & 3) * 8;     // bf16 elems
  const bf16_t* bsrc0 = Bp + (size_t)(n0 + w*32 + srow)*K + schk;
  const bf16_t* bsrc1 = bsrc0 + (size_t)16*K;

  auto stageB = [&](int buf, int k0){
    gload16(bsrc0 + k0, &Bs[buf][(w*32     )*32]);
    gload16(bsrc1 + k0, &Bs[buf][(w*32 + 16)*32]);
  };

  // EPI=1 A staging (bf16)
  const bf16_t* asrc0 = (const bf16_t*)Ap + (size_t)(m0 + w*32 + srow)*K + schk;
  const bf16_t* asrc1 = asrc0 + (size_t)16*K;
  auto stageA1 = [&](int buf, int k0){
    gload16(asrc0 + k0, &As[buf][(w*32     )*32]);
    gload16(asrc1 + k0, &As[buf][(w*32 + 16)*32]);
  };

  // EPI=0 A path: reg-staged f32 -> bf16
  const int a_row  = tid >> 1;
  const int a_half = tid & 1;
  f32x4 sAf[4];
  auto loadA0 = [&](int k0){
    const float* A = (const float*)Ap;
    int gr = m0 + a_row;
    if (gr < M) {
      const f32x4* p = (const f32x4*)(A + (size_t)gr*K + k0 + a_half*16);
      sAf[0]=p[0]; sAf[1]=p[1]; sAf[2]=p[2]; sAf[3]=p[3];
    } else {
      sAf[0]=fzero; sAf[1]=fzero; sAf[2]=fzero; sAf[3]=fzero;
    }
  };
  auto writeA0 = [&](){
    bf16x8 lo, hi;
#pragma unroll
    for (int j = 0; j < 4; ++j) {
      lo[j]   = (bf16_t)sAf[0][j];
      lo[4+j] = (bf16_t)sAf[1][j];
      hi[j]   = (bf16_t)sAf[2][j];
      hi[4+j] = (bf16_t)sAf[3][j];
    }
    *(bf16x8*)&As[0][a_row*32 + a_half*16    ] = lo;
    *(bf16x8*)&As[0][a_row*32 + a_half*16 + 8] = hi;
  };

  const int fr = lane & 15;
  const int kh = lane >> 4;        // 0..3 k-chunk
  constexpr int NT = K / 32;

  if constexpr (EPI == 0) {
    loadA0(0);
    stageB(0, 0);
#pragma unroll 4
    for (int kt = 0; kt < NT; ++kt) {
      const int cur = kt & 1;
      __syncthreads();                     // prev readers done; As free
      writeA0();
      __syncthreads();                     // As visible; Bs[cur] drained
      if (kt + 1 < NT) { loadA0((kt+1)*32); stageB(cur^1, (kt+1)*32); }
      bf16x8 a[4], b[4];
#pragma unroll
      for (int m = 0; m < 4; ++m)
        a[m] = *(const bf16x8*)&As[0][(wr*64 + m*16 + fr)*32 + kh*8];
#pragma unroll
      for (int n = 0; n < 4; ++n)
        b[n] = *(const bf16x8*)&Bs[cur][(wc*64 + n*16 + fr)*32 + kh*8];
#pragma unroll
      for (int m = 0; m < 4; ++m)
#pragma unroll
        for (int n = 0; n < 4; ++n)
          acc[m][n] = __builtin_amdgcn_mfma_f32_16x16x32_bf16(a[m], b[n], acc[m][n], 0, 0, 0);
    }
  } else {
    stageA1(0, 0);
    stageB(0, 0);
#pragma unroll 4
    for (int kt = 0; kt < NT; ++kt) {
      const int cur = kt & 1;
      __syncthreads();                     // buf[cur] staged & free of old readers
      if (kt + 1 < NT) { stageA1(cur^1, (kt+1)*32); stageB(cur^1, (kt+1)*32); }  // overlaps MFMA
      bf16x8 a[4], b[4];
#pragma unroll
      for (int m = 0; m < 4; ++m)
        a[m] = *(const bf16x8*)&As[cur][(wr*64 + m*16 + fr)*32 + kh*8];
#pragma unroll
      for (int n = 0; n < 4; ++n)
        b[n] = *(const bf16x8*)&Bs[cur][(wc*64 + n*16 + fr)*32 + kh*8];
#pragma unroll
      for (int m = 0; m < 4; ++m)
#pragma unroll
        for (int n = 0; n < 4; ++n)
          acc[m][n] = __builtin_amdgcn_mfma_f32_16x16x32_bf16(a[m], b[n], acc[m][n], 0, 0, 0);
    }
  }

  const int rg = lane >> 4;
  if constexpr (EPI == 0) {
#pragma unroll
    for (int n = 0; n < 4; ++n) {
      int col = n0 + wc*64 + n*16 + fr;
      float bv = bias[col];
#pragma unroll
      for (int m = 0; m < 4; ++m)
#pragma unroll
        for (int rr = 0; rr < 4; ++rr) {
          int row = m0 + wr*64 + m*16 + rg*4 + rr;
          if (row < M) {
            float v = acc[m][n][rr] + bv;
            Xout[(size_t)row*512 + col] = (bf16_t)(v > 0.f ? v : 0.f);
          }
        }
    }
  } else {
    float gacc[4][4];
#pragma unroll
    for (int m = 0; m < 4; ++m)
#pragma unroll
      for (int rr = 0; rr < 4; ++rr) gacc[m][rr] = 0.f;
    const bool even = (lane & 1) == 0;
#pragma unroll
    for (int n = 0; n < 4; ++n) {
      int col = n0 + wc*64 + n*16 + fr;
      float ucv = Uc[col >> 1];            // same for both lanes of a pair
#pragma unroll
      for (int m = 0; m < 4; ++m)
#pragma unroll
        for (int rr = 0; rr < 4; ++rr) {
          float v = acc[m][n][rr];
          // even lane holds a-val -> tanh; odd lane holds b-val -> sigmoid (1 trans/lane)
          float tv = even ? fast_tanh(v) : fast_sigmoid(v);
          float pv = __shfl_xor(tv, 1);
          gacc[m][rr] += tv * pv * ucv;    // duplicated on the pair; halved at the end
        }
    }
#pragma unroll
    for (int m = 0; m < 4; ++m)
#pragma unroll
      for (int rr = 0; rr < 4; ++rr) {
        float s = gacc[m][rr];
        s += __shfl_xor(s, 1);
        s += __shfl_xor(s, 2);
        s += __shfl_xor(s, 4);
        s += __shfl_xor(s, 8);
        if (fr == 0) {
          int row = m0 + wr*64 + m*16 + rg*4 + rr;
          if (row < M) atomicAdd(&Alogit[row], 0.5f * s);
        }
      }
  }
}

// ---------- A = sigmoid(Alogit); write to out; accumulate sumA ----------
__global__ void a_final(const float* __restrict__ Alogit, float* __restrict__ outA,
                        float* __restrict__ sumA){
  int i = blockIdx.x*256 + threadIdx.x;
  float a = 0.f;
  if (i < MINST) { a = fast_sigmoid(Alogit[i]); outA[i] = a; }
  float s = a;
#pragma unroll
  for (int o = 1; o < 64; o <<= 1) s += __shfl_xor(s, o);
  __shared__ float wsum[4];
  int lane = threadIdx.x & 63, w = threadIdx.x >> 6;
  if (lane == 0) wsum[w] = s;
  __syncthreads();
  if (threadIdx.x == 0) atomicAdd(sumA, wsum[0]+wsum[1]+wsum[2]+wsum[3]);
}

// ---------- M[512] = sum_i A_i * x_i (bf16x8 per lane) ----------
__global__ void m_reduce(const bf16_t* __restrict__ Xb, const float* __restrict__ Aout,
                         float* __restrict__ Mbuf){
  int t = threadIdx.x;
  int c0 = (t & 63) * 8;
  float acc[8];
#pragma unroll
  for (int j = 0; j < 8; ++j) acc[j] = 0.f;
  for (int r = blockIdx.x*4 + (t>>6); r < MINST; r += gridDim.x*4) {
    float a = Aout[r];
    bf16x8 xv = *(const bf16x8*)(Xb + (size_t)r*512 + c0);
#pragma unroll
    for (int j = 0; j < 8; ++j) acc[j] += a * (float)xv[j];
  }
#pragma unroll
  for (int j = 0; j < 8; ++j) atomicAdd(&Mbuf[c0 + j], acc[j]);
}

__device__ __forceinline__ float block_sum256(float v, float* red){
  int t = threadIdx.x;
  red[t] = v; __syncthreads();
  for (int s = 128; s > 0; s >>= 1) {
    if (t < s) red[t] += red[t+s];
    __syncthreads();
  }
  float rr = red[0];
  __syncthreads();
  return rr;
}

// ---------- VQ + classifier tail, single block ----------
__global__ __launch_bounds__(256)
void finalize_k(const float* __restrict__ Mbuf, const float* __restrict__ cb,
                const float* __restrict__ clsW, const float* __restrict__ clsb,
                float* __restrict__ dout)
{
  __shared__ float Mn[512];
  __shared__ float red[256];
  __shared__ float dist[256];
  __shared__ int   idxs[256];
  __shared__ int   indS;
  int t = threadIdx.x;
  float sA = Mbuf[512];
  Mn[t]     = Mbuf[t]     / sA;
  Mn[t+256] = Mbuf[t+256] / sA;
  __syncthreads();
  float msq_p = Mn[t]*Mn[t] + Mn[t+256]*Mn[t+256];
  float Msq = block_sum256(msq_p, red);

  const float* cbr = cb + t*512;
  float cs = 0.f, dt = 0.f;
  for (int k = 0; k < 512; k += 4) {
    f32x4 c = *(const f32x4*)(cbr + k);
    cs += c[0]*c[0] + c[1]*c[1] + c[2]*c[2] + c[3]*c[3];
    dt += Mn[k]*c[0] + Mn[k+1]*c[1] + Mn[k+2]*c[2] + Mn[k+3]*c[3];
  }
  // faithful to reference (sign bug kept): dist = |M|^2 + |cb|^2 + 2*M.cb
  dist[t] = Msq + cs + 2.f*dt;
  idxs[t] = t;
  __syncthreads();
  for (int s = 128; s > 0; s >>= 1) {
    if (t < s && dist[t+s] < dist[t]) { dist[t] = dist[t+s]; idxs[t] = idxs[t+s]; }
    __syncthreads();
  }
  if (t == 0) indS = idxs[0];
  __syncthreads();

  const float* qv = cb + (size_t)indS*512;
  float d0 = qv[t]     - Mn[t];
  float d1 = qv[t+256] - Mn[t+256];
  float vqs = block_sum256(d0*d0 + d1*d1, red);
  float vq_loss = 1.25f * (vqs / 512.f);

  float p0 = Mn[t]*clsW[t*2]   + Mn[t+256]*clsW[(t+256)*2];
  float p1 = Mn[t]*clsW[t*2+1] + Mn[t+256]*clsW[(t+256)*2+1];
  float l0 = block_sum256(p0, red);
  float l1 = block_sum256(p1, red);

  if (t == 0) {
    l0 += clsb[0]; l1 += clsb[1];
    float mx = fmaxf(l0, l1);
    float e0 = __expf(l0 - mx), e1 = __expf(l1 - mx);
    float si = e0 + e1;
    float y0 = e0 / si, y1 = e1 / si;
    int yhat = (l1 > l0) ? 1 : 0;
    dout[0] = l0; dout[1] = l1;
    dout[2] = y0; dout[3] = y1;
    dout[4] = (float)yhat;
    dout[5] = vq_loss;
    dout[6] = y0; dout[7] = y1;
  }
}

extern "C" void kernel_launch(void* const* d_in, const int* in_sizes, int n_in,
                              void* d_out, int out_size, void* d_ws, size_t ws_size,
                              hipStream_t stream) {
  const float* h    = (const float*)d_in[0];
  const float* fcW  = (const float*)d_in[1];
  const float* fcb  = (const float*)d_in[2];
  const float* Ua   = (const float*)d_in[3];
  const float* Ub   = (const float*)d_in[4];
  const float* Uc   = (const float*)d_in[5];
  const float* clsW = (const float*)d_in[6];
  const float* clsb = (const float*)d_in[7];
  const float* cbk  = (const float*)d_in[8];
  float* out = (float*)d_out;

  char* ws = (char*)d_ws;
  bf16_t* Xb     = (bf16_t*)ws;                       // 50000*512*2  = 51,200,000 B
  bf16_t* WT     = (bf16_t*)(ws + 51200000);          // 512*1024*2   (also OOB-read spill area)
  bf16_t* UabT   = (bf16_t*)(ws + 52248576);          // 2048*512*2
  float*  Alogit = (float*)(ws + 54345728);           // 50000*4
  float*  Mbuf   = (float*)(ws + 54545728);           // 513*4

  const int M = MINST;

  prep_wt <<<2048, 256, 0, stream>>>(fcW, WT);
  prep_uab<<<4096, 256, 0, stream>>>(Ua, Ub, UabT);
  zero_ws_k<<<196, 256, 0, stream>>>(Alogit, Mbuf);

  // fc + relu: x = relu(h @ W + b), bf16 out.  391 row-panels x 4 col-blocks.
  gemm_k<0,1024,4><<<1564, 256, 0, stream>>>(h, WT, M, fcb, Xb, nullptr, nullptr);
  // attention: Alogit += sum tanh(a)*sig(b)*Uc.  391 row-panels x 16 col-blocks.
  gemm_k<1, 512,16><<<6256, 256, 0, stream>>>(Xb, UabT, M, nullptr, nullptr, Uc, Alogit);

  a_final <<<196, 256, 0, stream>>>(Alogit, out + 8, Mbuf + 512);
  m_reduce<<<128, 256, 0, stream>>>(Xb, out + 8, Mbuf);
  finalize_k<<<1, 256, 0, stream>>>(Mbuf, cbk, clsW, clsb, out);
}

// Round 3
// 505.871 us; speedup vs baseline: 1.0025x; 1.0025x over previous
//
#include <hip/hip_runtime.h>
#include <hip/hip_bf16.h>
#include <math.h>

typedef __bf16 bf16_t;
typedef __bf16 bf16x8 __attribute__((ext_vector_type(8)));
typedef float  f32x4  __attribute__((ext_vector_type(4)));

#define MINST 50000

typedef const __attribute__((address_space(1))) void* gas1_t;
typedef __attribute__((address_space(3))) void* las3_t;
__device__ __forceinline__ void gload16(const void* g, const void* l){
  __builtin_amdgcn_global_load_lds((gas1_t)g, (las3_t)l, 16, 0, 0);
}

__device__ __forceinline__ float fast_sigmoid(float x){
  return __fdividef(1.f, 1.f + __expf(-x));
}
__device__ __forceinline__ float fast_tanh(float x){
  float e = __expf(2.f*x);
  return 1.f - __fdividef(2.f, e + 1.f);
}

// ---------- prep: W[1024][512] -> WT[512][1024] bf16 ----------
__global__ void prep_wt(const float* __restrict__ W, bf16_t* __restrict__ WT){
  int idx = blockIdx.x*256 + threadIdx.x;
  if (idx >= 512*1024) return;
  int n = idx >> 10, k = idx & 1023;
  WT[idx] = (bf16_t)W[k*512 + n];
}

// ---------- prep: Ua/Ub[4][512][256] -> UabT[2048][512] bf16, cols interleaved ----------
__global__ void prep_uab(const float* __restrict__ Ua, const float* __restrict__ Ub,
                         bf16_t* __restrict__ UabT){
  int idx = blockIdx.x*256 + threadIdx.x;
  if (idx >= 2048*512) return;
  int c = idx >> 9, k = idx & 511;
  int s = c & 1, t = c >> 1;
  int n = t >> 8, l = t & 255;
  const float* src = s ? Ub : Ua;
  UabT[idx] = (bf16_t)src[(n*512 + k)*256 + l];
}

__global__ void zero_ws_k(float* __restrict__ Alogit, float* __restrict__ Mbuf){
  int i = blockIdx.x*256 + threadIdx.x;
  if (i < MINST) Alogit[i] = 0.f;
  if (i < 513)   Mbuf[i]  = 0.f;
}

// ---------- MFMA GEMM, 128x128 tile, BK=64, 4 waves (2x2) ----------
// LDS linear [128][64] bf16; XOR swizzle (chunk ^= row&7, 16B units) applied on the
// global source address (stage side) and on ds_read (read side) -> conflict-free.
// EPI=0: A f32 reg-staged cvt (swizzled ds_write), B gload dbuf. relu+bias -> bf16.
// EPI=1: A,B both gload single-buffer, attention epilogue.
template<int EPI, int K, int NBY>
__global__ __launch_bounds__(256, 2)
void gemm_k(const void* __restrict__ Ap, const bf16_t* __restrict__ Bp, int M,
            const float* __restrict__ bias, bf16_t* __restrict__ Xout,
            const float* __restrict__ Uc, float* __restrict__ Alogit)
{
  constexpr int NBUFB = (EPI==0 ? 2 : 1);
  __shared__ bf16_t As[128*64] __attribute__((aligned(16)));
  __shared__ bf16_t Bs[NBUFB][128*64] __attribute__((aligned(16)));

  const int tid  = threadIdx.x;
  const int lane = tid & 63;
  const int w    = tid >> 6;
  const int wr   = w >> 1;
  const int wc   = w & 1;

  // bijective XCD-chunk swizzle, panel-major logical order
  const int nwg = gridDim.x;
  const int q = nwg >> 3, r = nwg & 7;
  const int x = blockIdx.x & 7, pos = blockIdx.x >> 3;
  const int logical = (x < r ? x*(q+1) : r*(q+1) + (x-r)*q) + pos;
  const int m0 = (logical / NBY) * 128;
  const int n0 = (logical % NBY) * 128;

  const f32x4 fzero = {0.f, 0.f, 0.f, 0.f};
  f32x4 acc[4][4];
#pragma unroll
  for (int m = 0; m < 4; ++m)
#pragma unroll
    for (int n = 0; n < 4; ++n) acc[m][n] = fzero;

  // staging geometry: one gload16 covers 8 rows x 128B; lane -> (row=lane>>3, chunk=lane&7)
  const int sR = lane >> 3;                 // row within 8-row group
  const int sC = (lane & 7) ^ sR;           // pre-swizzled source chunk (16B units)

  auto stageB = [&](int kt, int buf){
#pragma unroll
    for (int j = 0; j < 4; ++j) {
      int rL = w*32 + j*8;
      gload16(Bp + (size_t)(n0 + rL + sR)*K + kt*64 + sC*8, &Bs[buf][rL*64]);
    }
  };
  auto stageA1 = [&](int kt){
    const bf16_t* Ab = (const bf16_t*)Ap;
#pragma unroll
    for (int j = 0; j < 4; ++j) {
      int rL = w*32 + j*8;
      gload16(Ab + (size_t)(m0 + rL + sR)*K + kt*64 + sC*8, &As[rL*64]);
    }
  };

  // EPI=0 A path: reg-staged f32 -> bf16, swizzled ds_write
  const int a_row  = tid >> 1;              // 0..127
  const int a_half = tid & 1;               // which 32-elem half of the 64-col row
  f32x4 sAf[8];
  auto loadA0 = [&](int kt){
    const float* A = (const float*)Ap;
    int gr = m0 + a_row;
    if (gr < M) {
      const f32x4* p = (const f32x4*)(A + (size_t)gr*K + kt*64 + a_half*32);
#pragma unroll
      for (int j = 0; j < 8; ++j) sAf[j] = p[j];
    } else {
#pragma unroll
      for (int j = 0; j < 8; ++j) sAf[j] = fzero;
    }
  };
  auto writeA0 = [&](){
#pragma unroll
    for (int j = 0; j < 4; ++j) {
      bf16x8 v;
#pragma unroll
      for (int e = 0; e < 4; ++e) { v[e] = (bf16_t)sAf[2*j][e]; v[4+e] = (bf16_t)sAf[2*j+1][e]; }
      int c = (a_half*4 + j) ^ (a_row & 7);
      *(bf16x8*)&As[a_row*64 + c*8] = v;
    }
  };

  const int fr = lane & 15;
  const int kh = lane >> 4;                 // 0..3 (8-elem chunk within 32-elem k-step)
  auto readFrags = [&](int buf, bf16x8 (&a)[4][2], bf16x8 (&b)[4][2]){
#pragma unroll
    for (int m = 0; m < 4; ++m){
      int R = wr*64 + m*16 + fr;
#pragma unroll
      for (int ks = 0; ks < 2; ++ks){
        int c = ((ks<<2)|kh) ^ (R & 7);
        a[m][ks] = *(const bf16x8*)&As[R*64 + c*8];
      }
    }
#pragma unroll
    for (int n = 0; n < 4; ++n){
      int R = wc*64 + n*16 + fr;
#pragma unroll
      for (int ks = 0; ks < 2; ++ks){
        int c = ((ks<<2)|kh) ^ (R & 7);
        b[n][ks] = *(const bf16x8*)&Bs[buf][R*64 + c*8];
      }
    }
  };

  constexpr int NT = K / 64;

  if constexpr (EPI == 0) {
    loadA0(0); stageB(0, 0);
    for (int kt = 0; kt < NT; ++kt) {
      const int cur = kt & 1;
      __syncthreads();                        // Bs[cur] staged (vmcnt drain); prev As readers done
      writeA0();
      __syncthreads();                        // As visible
      if (kt + 1 < NT) { loadA0(kt+1); stageB(kt+1, cur^1); }
      bf16x8 a[4][2], b[4][2];
      readFrags(cur, a, b);
#pragma unroll
      for (int ks = 0; ks < 2; ++ks)
#pragma unroll
        for (int m = 0; m < 4; ++m)
#pragma unroll
          for (int n = 0; n < 4; ++n)
            acc[m][n] = __builtin_amdgcn_mfma_f32_16x16x32_bf16(a[m][ks], b[n][ks], acc[m][n], 0, 0, 0);
    }
  } else {
    stageA1(0); stageB(0, 0);
    for (int kt = 0; kt < NT; ++kt) {
      __syncthreads();                        // tile kt staged (vmcnt drain); prev readers done
      bf16x8 a[4][2], b[4][2];
      readFrags(0, a, b);
      __syncthreads();                        // reads complete -> buffers free
      if (kt + 1 < NT) { stageA1(kt+1); stageB(kt+1, 0); }   // overlaps MFMA below
#pragma unroll
      for (int ks = 0; ks < 2; ++ks)
#pragma unroll
        for (int m = 0; m < 4; ++m)
#pragma unroll
          for (int n = 0; n < 4; ++n)
            acc[m][n] = __builtin_amdgcn_mfma_f32_16x16x32_bf16(a[m][ks], b[n][ks], acc[m][n], 0, 0, 0);
    }
  }

  const int rg = lane >> 4;
  if constexpr (EPI == 0) {
#pragma unroll
    for (int n = 0; n < 4; ++n) {
      int col = n0 + wc*64 + n*16 + fr;
      float bv = bias[col];
#pragma unroll
      for (int m = 0; m < 4; ++m)
#pragma unroll
        for (int rr = 0; rr < 4; ++rr) {
          int row = m0 + wr*64 + m*16 + rg*4 + rr;
          if (row < M) {
            float v = acc[m][n][rr] + bv;
            Xout[(size_t)row*512 + col] = (bf16_t)(v > 0.f ? v : 0.f);
          }
        }
    }
  } else {
    float gacc[4][4];
#pragma unroll
    for (int m = 0; m < 4; ++m)
#pragma unroll
      for (int rr = 0; rr < 4; ++rr) gacc[m][rr] = 0.f;
    const bool even = (lane & 1) == 0;
#pragma unroll
    for (int n = 0; n < 4; ++n) {
      int col = n0 + wc*64 + n*16 + fr;
      float ucv = Uc[col >> 1];               // same for both lanes of a pair
#pragma unroll
      for (int m = 0; m < 4; ++m)
#pragma unroll
        for (int rr = 0; rr < 4; ++rr) {
          float v = acc[m][n][rr];
          // even lane holds a-val -> tanh; odd lane holds b-val -> sigmoid (1 trans/lane)
          float tv = even ? fast_tanh(v) : fast_sigmoid(v);
          float pv = __shfl_xor(tv, 1);
          gacc[m][rr] += tv * pv * ucv;       // duplicated on the pair; halved at the end
        }
    }
#pragma unroll
    for (int m = 0; m < 4; ++m)
#pragma unroll
      for (int rr = 0; rr < 4; ++rr) {
        float s = gacc[m][rr];
        s += __shfl_xor(s, 1);
        s += __shfl_xor(s, 2);
        s += __shfl_xor(s, 4);
        s += __shfl_xor(s, 8);
        if (fr == 0) {
          int row = m0 + wr*64 + m*16 + rg*4 + rr;
          if (row < M) atomicAdd(&Alogit[row], 0.5f * s);
        }
      }
  }
}

// ---------- A = sigmoid(Alogit); write to out; accumulate sumA ----------
__global__ void a_final(const float* __restrict__ Alogit, float* __restrict__ outA,
                        float* __restrict__ sumA){
  int i = blockIdx.x*256 + threadIdx.x;
  float a = 0.f;
  if (i < MINST) { a = fast_sigmoid(Alogit[i]); outA[i] = a; }
  float s = a;
#pragma unroll
  for (int o = 1; o < 64; o <<= 1) s += __shfl_xor(s, o);
  __shared__ float wsum[4];
  int lane = threadIdx.x & 63, w = threadIdx.x >> 6;
  if (lane == 0) wsum[w] = s;
  __syncthreads();
  if (threadIdx.x == 0) atomicAdd(sumA, wsum[0]+wsum[1]+wsum[2]+wsum[3]);
}

// ---------- M[512] = sum_i A_i * x_i (bf16x8 per lane) ----------
__global__ void m_reduce(const bf16_t* __restrict__ Xb, const float* __restrict__ Aout,
                         float* __restrict__ Mbuf){
  int t = threadIdx.x;
  int c0 = (t & 63) * 8;
  float acc[8];
#pragma unroll
  for (int j = 0; j < 8; ++j) acc[j] = 0.f;
  for (int r = blockIdx.x*4 + (t>>6); r < MINST; r += gridDim.x*4) {
    float a = Aout[r];
    bf16x8 xv = *(const bf16x8*)(Xb + (size_t)r*512 + c0);
#pragma unroll
    for (int j = 0; j < 8; ++j) acc[j] += a * (float)xv[j];
  }
#pragma unroll
  for (int j = 0; j < 8; ++j) atomicAdd(&Mbuf[c0 + j], acc[j]);
}

__device__ __forceinline__ float block_sum256(float v, float* red){
  int t = threadIdx.x;
  red[t] = v; __syncthreads();
  for (int s = 128; s > 0; s >>= 1) {
    if (t < s) red[t] += red[t+s];
    __syncthreads();
  }
  float rr = red[0];
  __syncthreads();
  return rr;
}

// ---------- VQ + classifier tail, single block ----------
__global__ __launch_bounds__(256)
void finalize_k(const float* __restrict__ Mbuf, const float* __restrict__ cb,
                const float* __restrict__ clsW, const float* __restrict__ clsb,
                float* __restrict__ dout)
{
  __shared__ float Mn[512];
  __shared__ float red[256];
  __shared__ float dist[256];
  __shared__ int   idxs[256];
  __shared__ int   indS;
  int t = threadIdx.x;
  float sA = Mbuf[512];
  Mn[t]     = Mbuf[t]     / sA;
  Mn[t+256] = Mbuf[t+256] / sA;
  __syncthreads();
  float msq_p = Mn[t]*Mn[t] + Mn[t+256]*Mn[t+256];
  float Msq = block_sum256(msq_p, red);

  const float* cbr = cb + t*512;
  float cs = 0.f, dt = 0.f;
  for (int k = 0; k < 512; k += 4) {
    f32x4 c = *(const f32x4*)(cbr + k);
    cs += c[0]*c[0] + c[1]*c[1] + c[2]*c[2] + c[3]*c[3];
    dt += Mn[k]*c[0] + Mn[k+1]*c[1] + Mn[k+2]*c[2] + Mn[k+3]*c[3];
  }
  // faithful to reference (sign bug kept): dist = |M|^2 + |cb|^2 + 2*M.cb
  dist[t] = Msq + cs + 2.f*dt;
  idxs[t] = t;
  __syncthreads();
  for (int s = 128; s > 0; s >>= 1) {
    if (t < s && dist[t+s] < dist[t]) { dist[t] = dist[t+s]; idxs[t] = idxs[t+s]; }
    __syncthreads();
  }
  if (t == 0) indS = idxs[0];
  __syncthreads();

  const float* qv = cb + (size_t)indS*512;
  float d0 = qv[t]     - Mn[t];
  float d1 = qv[t+256] - Mn[t+256];
  float vqs = block_sum256(d0*d0 + d1*d1, red);
  float vq_loss = 1.25f * (vqs / 512.f);

  float p0 = Mn[t]*clsW[t*2]   + Mn[t+256]*clsW[(t+256)*2];
  float p1 = Mn[t]*clsW[t*2+1] + Mn[t+256]*clsW[(t+256)*2+1];
  float l0 = block_sum256(p0, red);
  float l1 = block_sum256(p1, red);

  if (t == 0) {
    l0 += clsb[0]; l1 += clsb[1];
    float mx = fmaxf(l0, l1);
    float e0 = __expf(l0 - mx), e1 = __expf(l1 - mx);
    float si = e0 + e1;
    float y0 = e0 / si, y1 = e1 / si;
    int yhat = (l1 > l0) ? 1 : 0;
    dout[0] = l0; dout[1] = l1;
    dout[2] = y0; dout[3] = y1;
    dout[4] = (float)yhat;
    dout[5] = vq_loss;
    dout[6] = y0; dout[7] = y1;
  }
}

extern "C" void kernel_launch(void* const* d_in, const int* in_sizes, int n_in,
                              void* d_out, int out_size, void* d_ws, size_t ws_size,
                              hipStream_t stream) {
  const float* h    = (const float*)d_in[0];
  const float* fcW  = (const float*)d_in[1];
  const float* fcb  = (const float*)d_in[2];
  const float* Ua   = (const float*)d_in[3];
  const float* Ub   = (const float*)d_in[4];
  const float* Uc   = (const float*)d_in[5];
  const float* clsW = (const float*)d_in[6];
  const float* clsb = (const float*)d_in[7];
  const float* cbk  = (const float*)d_in[8];
  float* out = (float*)d_out;

  char* ws = (char*)d_ws;
  bf16_t* Xb     = (bf16_t*)ws;                       // 50000*512*2 (tail rows of last tile
                                                      //  read harmlessly into WT region)
  bf16_t* WT     = (bf16_t*)(ws + 51200000);          // 512*1024*2
  bf16_t* UabT   = (bf16_t*)(ws + 52248576);          // 2048*512*2
  float*  Alogit = (float*)(ws + 54345728);           // 50000*4
  float*  Mbuf   = (float*)(ws + 54545728);           // 513*4

  const int M = MINST;

  prep_wt <<<2048, 256, 0, stream>>>(fcW, WT);
  prep_uab<<<4096, 256, 0, stream>>>(Ua, Ub, UabT);
  zero_ws_k<<<196, 256, 0, stream>>>(Alogit, Mbuf);

  // fc + relu: x = relu(h @ W + b), bf16 out.  391 row-panels x 4 col-blocks.
  gemm_k<0,1024,4><<<1564, 256, 0, stream>>>(h, WT, M, fcb, Xb, nullptr, nullptr);
  // attention: Alogit += sum tanh(a)*sig(b)*Uc.  391 row-panels x 16 col-blocks.
  gemm_k<1, 512,16><<<6256, 256, 0, stream>>>(Xb, UabT, M, nullptr, nullptr, Uc, Alogit);

  a_final <<<196, 256, 0, stream>>>(Alogit, out + 8, Mbuf + 512);
  m_reduce<<<128, 256, 0, stream>>>(Xb, out + 8, Mbuf);
  finalize_k<<<1, 256, 0, stream>>>(Mbuf, cbk, clsW, clsb, out);
}